// Round 2
// baseline (5132.710 us; speedup 1.0000x reference)
//
#include <hip/hip_runtime.h>

typedef __bf16 bf16x8 __attribute__((ext_vector_type(8)));
typedef unsigned short ushort8_t __attribute__((ext_vector_type(8)));
typedef float f32x4 __attribute__((ext_vector_type(4)));
typedef unsigned int uint4_t __attribute__((ext_vector_type(4)));

#define MFMA16(a,b,c) __builtin_amdgcn_mfma_f32_16x16x32_bf16((a),(b),(c),0,0,0)

// Sizes (hard-coded from reference): B=512, T=1024, Din=128, H=512, Dout=128
// ws layout: [0, 294912): streamed B-frags, 16 waves x 18 frags x 64 lanes x 16B
//            [294912, +2048): bias fp32[512] = bx + bh

__device__ __forceinline__ unsigned short f2bf(float f) {
  unsigned int u = __float_as_uint(f);
  u += 0x7FFFu + ((u >> 16) & 1u);   // RTNE
  return (unsigned short)(u >> 16);
}

__device__ __forceinline__ bf16x8 pack8(const float* __restrict__ s) {
  ushort8_t u;
#pragma unroll
  for (int j = 0; j < 8; ++j) u[j] = f2bf(s[j]);
  return __builtin_bit_cast(bf16x8, u);
}

// ---------------- prep: repack streamed weights (bf16 frag order) + bias ----
__global__ void rnn_prep(const float* __restrict__ Wx, const float* __restrict__ bx,
                         const float* __restrict__ Wh, const float* __restrict__ bh,
                         void* __restrict__ ws) {
  int gid = blockIdx.x * 256 + threadIdx.x;
  if (blockIdx.x < 72) {
    // chunk gid in [0, 18432): gid = (w*18 + f)*64 + l
    int l = gid & 63;
    int f = (gid >> 6) % 18;
    int w = gid / (64 * 18);
    int nt = f & 1, fi = f >> 1;
    int n = w * 32 + nt * 16 + (l & 15);
    int kg = l >> 4;
    const float* src;
    if (fi < 5) src = Wh + (size_t)n * 512 + (11 + fi) * 32 + kg * 8;  // Wh k-tiles 11..15
    else        src = Wx + (size_t)n * 128 + (fi - 5) * 32 + kg * 8;   // Wx k-tiles 0..3
    ushort8_t u;
#pragma unroll
    for (int j = 0; j < 8; ++j) u[j] = f2bf(src[j]);
    ((ushort8_t*)ws)[gid] = u;
  } else {
    int i = (gid - 72 * 256) * 2;
    float* bias = (float*)((char*)ws + 294912);
    bias[i]     = bx[i] + bh[i];
    bias[i + 1] = bx[i + 1] + bh[i + 1];
  }
}

// ---------------- main persistent scan kernel ------------------------------
// grid = 32 blocks (one per 16 batch rows), 1024 threads (16 waves).
// wave w owns H-columns [32w, 32w+32). 11 Wh k-tiles resident in VGPRs,
// 5 Wh + 4 Wx k-tiles streamed from ws (L2-resident). h double-buffered in LDS.
__global__ __launch_bounds__(1024) void rnn_scan(
    const float* __restrict__ x, const float* __restrict__ Wh,
    const float* __restrict__ Wy, const float* __restrict__ by,
    const void* __restrict__ ws, float* __restrict__ out) {
  __shared__ alignas(16) char h_lds[32768];  // 2 x [16][512] bf16, swizzled
  __shared__ alignas(16) char x_lds[8192];   // 2 x [16][128] bf16, swizzled

  const int tid = threadIdx.x;
  const int w = tid >> 6, l = tid & 63;
  const int m = l & 15, kg = l >> 4;
  const int sw = (m & 7) << 4;
  const int bb = blockIdx.x << 4;

  // swizzled LDS layout: F(row,k) = row*RS + ((k>>6)<<7) + ((2*(k&63)) ^ ((row&7)<<4))
  const int hE = m * 1024 + ((kg * 16) ^ sw);
  const int hO = m * 1024 + ((64 + kg * 16) ^ sw);
  const int xE = m * 256 + ((kg * 16) ^ sw);
  const int xO = m * 256 + ((64 + kg * 16) ^ sw);

  // x staging: wave w stages batch row (bb+w), elements k=2l,2l+1
  const float* xrow = x + (size_t)(bb + w) * (1024 * 128) + 2 * l;
  const int k2 = 2 * l;
  const int xw_off = w * 256 + ((k2 >> 6) << 7) + ((2 * (k2 & 63)) ^ ((w & 7) << 4));

  // h-write constants: c = w*32 + nt*16 + m
  int cblk[2], ca2[2];
#pragma unroll
  for (int nt = 0; nt < 2; ++nt) {
    int c = w * 32 + nt * 16 + m;
    cblk[nt] = (c >> 6) << 7;
    ca2[nt] = 2 * (c & 63);
  }

  const float* bias = (const float*)((const char*)ws + 294912);
  const float b0 = bias[w * 32 + m];
  const float b1 = bias[w * 32 + 16 + m];

  // resident B fragments: Wh k-tiles 0..10 (88 VGPRs)
  bf16x8 bres[22];
#pragma unroll
  for (int kt = 0; kt < 11; ++kt)
#pragma unroll
    for (int nt = 0; nt < 2; ++nt)
      bres[kt * 2 + nt] = pack8(Wh + (size_t)(w * 32 + nt * 16 + m) * 512 + kt * 32 + kg * 8);

  const bf16x8* sp = (const bf16x8*)ws + (w * 18) * 64 + l;

  // zero h buffer 0 (h0 = 0); stage x(t=0)
  *(uint4_t*)(h_lds + tid * 16) = (uint4_t){0, 0, 0, 0};
  {
    float2 xv = *(const float2*)(xrow);
    unsigned int p = (unsigned)f2bf(xv.x) | ((unsigned)f2bf(xv.y) << 16);
    *(unsigned int*)(x_lds + xw_off) = p;
  }
  __syncthreads();

  for (int t = 0; t < 1024; ++t) {
    const int cur = t & 1, nxt = cur ^ 1;
    const char* hb = h_lds + cur * 16384;
    const char* xb = x_lds + cur * 4096;

    // defeat LICM of the (loop-invariant) streamed-weight loads: opaque ptr per iter
    unsigned long long spi = (unsigned long long)sp;
    asm volatile("" : "+v"(spi));
    const bf16x8* spv = (const bf16x8*)spi;

    // prefetch x for t+1 (consumed at end of step -> latency hidden)
    const int tt = (t < 1023) ? t + 1 : 1023;
    float2 xv = *(const float2*)(xrow + (size_t)tt * 128);

    f32x4 acc0 = {0.f, 0.f, 0.f, 0.f}, acc1 = {0.f, 0.f, 0.f, 0.f};

#pragma unroll
    for (int kt = 0; kt < 11; ++kt) {
      bf16x8 a = *(const bf16x8*)(hb + ((kt & 1) ? hO : hE) + (kt >> 1) * 128);
      acc0 = MFMA16(a, bres[kt * 2], acc0);
      acc1 = MFMA16(a, bres[kt * 2 + 1], acc1);
    }
#pragma unroll
    for (int fi = 0; fi < 9; ++fi) {
      const int kt = 11 + fi;
      bf16x8 sb0 = spv[(fi * 2) * 64];
      bf16x8 sb1 = spv[(fi * 2 + 1) * 64];
      bf16x8 a;
      if (kt < 16) {
        a = *(const bf16x8*)(hb + ((kt & 1) ? hO : hE) + (kt >> 1) * 128);
      } else {
        const int kx = kt - 16;
        a = *(const bf16x8*)(xb + ((kx & 1) ? xO : xE) + (kx >> 1) * 128);
      }
      acc0 = MFMA16(a, sb0, acc0);
      acc1 = MFMA16(a, sb1, acc1);
    }

    // stage x(t+1) into LDS for next step
    {
      unsigned int p = (unsigned)f2bf(xv.x) | ((unsigned)f2bf(xv.y) << 16);
      *(unsigned int*)(x_lds + nxt * 4096 + xw_off) = p;
    }

    // bias + tanh + write h_new (C/D layout: col=lane&15, row=(lane>>4)*4+reg)
    char* hn = h_lds + nxt * 16384;
#pragma unroll
    for (int nt = 0; nt < 2; ++nt) {
      const float bnt = nt ? b1 : b0;
      const f32x4 av = nt ? acc1 : acc0;
#pragma unroll
      for (int i = 0; i < 4; ++i) {
        const int r = kg * 4 + i;
        float pre = av[i] + bnt;
        float e = __expf(2.f * pre);
        float hv = 1.f - 2.f / (e + 1.f);   // tanh, saturates correctly at +/-inf
        const int off = r * 1024 + cblk[nt] + (ca2[nt] ^ ((r & 7) << 4));
        *(unsigned short*)(hn + off) = f2bf(hv);
      }
    }
    __syncthreads();
  }

  // epilogue: y = h_T @ Wy^T + by ; final h is in buffer 0 (t=1024 even)
  if (w < 8) {
    f32x4 aY = {0.f, 0.f, 0.f, 0.f};
#pragma unroll
    for (int kt = 0; kt < 16; ++kt) {
      bf16x8 a = *(const bf16x8*)(h_lds + ((kt & 1) ? hO : hE) + (kt >> 1) * 128);
      bf16x8 b = pack8(Wy + (size_t)(w * 16 + m) * 512 + kt * 32 + kg * 8);
      aY = MFMA16(a, b, aY);
    }
    const float bv = by[w * 16 + m];
#pragma unroll
    for (int i = 0; i < 4; ++i)
      out[(size_t)(bb + kg * 4 + i) * 128 + w * 16 + m] = aY[i] + bv;
  }
}

extern "C" void kernel_launch(void* const* d_in, const int* in_sizes, int n_in,
                              void* d_out, int out_size, void* d_ws, size_t ws_size,
                              hipStream_t stream) {
  const float* x  = (const float*)d_in[0];
  const float* Wx = (const float*)d_in[1];
  const float* bx = (const float*)d_in[2];
  const float* Wh = (const float*)d_in[3];
  const float* bh = (const float*)d_in[4];
  const float* Wy = (const float*)d_in[5];
  const float* by = (const float*)d_in[6];

  rnn_prep<<<73, 256, 0, stream>>>(Wx, bx, Wh, bh, d_ws);
  rnn_scan<<<32, 1024, 0, stream>>>(x, Wh, Wy, by, d_ws, (float*)d_out);
}